// Round 1
// baseline (193.676 us; speedup 1.0000x reference)
//
#include <hip/hip_runtime.h>
#include <math.h>

#define SRATE 32000.0
#define NB 128            // batch rows
#define NT 160000         // samples per row
#define CL 500            // chunk length
#define NC 320            // chunks per row (NT/CL)
#define GPB 5             // 64-chunk groups per row (NC/64)
#define STEP 100          // samples per LDS tile per lane
#define NSTEP 5           // CL/STEP

#ifndef M_PI
#define M_PI 3.14159265358979323846
#endif

// ---------------------------------------------------------------------------
// K1: coefficients (f64, same formula as reference) + H = M^CL (6x6 homogeneous
// state transition over one chunk) via binary matrix powering.
// State vector: (y1[n-1], y1[n-2], y2[n-1], y2[n-2], y3[n-1], y3[n-2])
// ---------------------------------------------------------------------------
__global__ __launch_bounds__(64) void eq_k1(
    const float* __restrict__ fr, const float* __restrict__ gn,
    const float* __restrict__ qs, float* __restrict__ fc,
    double* __restrict__ Hd)
{
  __shared__ double dc[24];
  __shared__ double Mb[36], Rb[36], Tb[36];
  const int t = threadIdx.x;
  if (t == 0) {
    for (int f = 0; f < 3; ++f) {
      double w0 = 2.0 * M_PI * (double)fr[f] / SRATE;
      double A  = exp((double)gn[f] / 40.0 * log(10.0));
      double al = sin(w0) / (2.0 * (double)qs[f]);
      double cw = cos(w0);
      double a0 = 1.0 + al / A;
      double b0 = (1.0 + al * A) / a0;
      double b1 = -2.0 * cw / a0;
      double b2 = (1.0 - al * A) / a0;
      double a1 = -2.0 * cw / a0;
      double a2 = (1.0 - al / A) / a0;
      dc[f*8+0]=b0; dc[f*8+1]=b1; dc[f*8+2]=b2; dc[f*8+3]=a1; dc[f*8+4]=a2;
      fc[f*8+0]=(float)b0; fc[f*8+1]=(float)b1; fc[f*8+2]=(float)b2;
      fc[f*8+3]=(float)a1; fc[f*8+4]=(float)a2;
    }
  }
  __syncthreads();
  // Build one-step matrix M column-by-column: one zero-input step from e_t.
  if (t < 6) {
    double s0=0,s1=0,s2=0,s3=0,s4=0,s5=0;
    if (t==0) s0=1; else if (t==1) s1=1; else if (t==2) s2=1;
    else if (t==3) s3=1; else if (t==4) s4=1; else s5=1;
    double y1 = -dc[3]*s0 - dc[4]*s1;
    double y2 = dc[8]*y1 + dc[9]*s0 + dc[10]*s1 - dc[11]*s2 - dc[12]*s3;
    double y3 = dc[16]*y2 + dc[17]*s2 + dc[18]*s3 - dc[19]*s4 - dc[20]*s5;
    Mb[0*6+t] = y1;  Mb[1*6+t] = s0;
    Mb[2*6+t] = y2;  Mb[3*6+t] = s2;
    Mb[4*6+t] = y3;  Mb[5*6+t] = s4;
  }
  if (t < 36) Rb[t] = ((t % 7) == 0) ? 1.0 : 0.0;  // identity
  __syncthreads();
  const int i = t / 6, j = t % 6;
  int e = CL;
  while (e) {
    if (e & 1) {                      // R = R * M
      double acc = 0.0;
      if (t < 36) { for (int k = 0; k < 6; ++k) acc += Rb[i*6+k]*Mb[k*6+j]; Tb[t]=acc; }
      __syncthreads();
      if (t < 36) Rb[t] = Tb[t];
      __syncthreads();
    }
    e >>= 1;
    if (e) {                          // M = M * M
      double acc = 0.0;
      if (t < 36) { for (int k = 0; k < 6; ++k) acc += Mb[i*6+k]*Mb[k*6+j]; Tb[t]=acc; }
      __syncthreads();
      if (t < 36) Mb[t] = Tb[t];
      __syncthreads();
    }
  }
  if (t < 36) Hd[t] = Rb[t];
}

// ---------------------------------------------------------------------------
// Shared tile machinery: 64 lanes x 128-float rows (32 KiB). Element (row s,
// in-tile sample j) lives at lds[s*128 + ((j/4 + s)&31)*4 + j%4] -- 4-float
// rotation keeps b128 ops 16B-aligned and spreads banks evenly (8 words/bank).
// ---------------------------------------------------------------------------

// K2: zero-state cascade per (row, chunk); emit 6-float exit state only.
__global__ __launch_bounds__(64) void eq_k2(
    const float* __restrict__ x, const float* __restrict__ fc,
    float* __restrict__ eout)
{
  __shared__ float lds[64 * 128];
  const int l = threadIdx.x;
  const int bid = blockIdx.x;
  const int r = bid / GPB, g = bid % GPB;
  const float b01=fc[0],  b11=fc[1],  b21=fc[2],  a11=fc[3],  a21=fc[4];
  const float b02=fc[8],  b12=fc[9],  b22=fc[10], a12=fc[11], a22=fc[12];
  const float b03=fc[16], b13=fc[17], b23=fc[18], a13=fc[19], a23=fc[20];
  const float* xr = x + (size_t)r * NT;
  const float* xg = xr + g * 64 * CL;
  const int chunk = g * 64 + l;
  const int t0 = chunk * CL;
  float x1 = 0.f, x2 = 0.f;
  if (t0 > 0) { x1 = xr[t0-1]; x2 = xr[t0-2]; }
  float y1p=0,y1pp=0,y2p=0,y2pp=0,y3p=0,y3pp=0;
  for (int st = 0; st < NSTEP; ++st) {
    const int j0 = st * STEP;
    __syncthreads();                   // protect tile reuse
    #pragma unroll
    for (int i = 0; i < 25; ++i) {     // cooperative coalesced load
      int f = i * 64 + l;
      int seg = f / 25, off = f % 25;
      float4 v = *(const float4*)(xg + seg*CL + j0 + off*4);
      *(float4*)(&lds[seg*128 + (((off + seg) & 31) << 2)]) = v;
    }
    __syncthreads();
    #pragma unroll
    for (int jq = 0; jq < 25; ++jq) {
      float4 xv = *(const float4*)(&lds[l*128 + (((jq + l) & 31) << 2)]);
      #pragma unroll
      for (int q = 0; q < 4; ++q) {
        const float xn = (q==0)?xv.x:(q==1)?xv.y:(q==2)?xv.z:xv.w;
        float y1 = b01*xn + b11*x1  + b21*x2   - a11*y1p - a21*y1pp;
        float y2 = b02*y1 + b12*y1p + b22*y1pp - a12*y2p - a22*y2pp;
        float y3 = b03*y2 + b13*y2p + b23*y2pp - a13*y3p - a23*y3pp;
        x2=x1; x1=xn;
        y1pp=y1p; y1p=y1; y2pp=y2p; y2p=y2; y3pp=y3p; y3p=y3;
      }
    }
  }
  float* ep = eout + ((size_t)chunk * NB + r) * 6;
  ep[0]=y1p; ep[1]=y1pp; ep[2]=y2p; ep[3]=y2pp; ep[4]=y3p; ep[5]=y3pp;
}

// K3: per-row sequential fixup sigma_{c+1} = e_c + H*sigma_c. 128 rows.
__global__ __launch_bounds__(32) void eq_k3(
    const float* __restrict__ eout, const double* __restrict__ Hd,
    float* __restrict__ sig)
{
  const int r = blockIdx.x * 32 + threadIdx.x;
  float H[36];
  #pragma unroll
  for (int i = 0; i < 36; ++i) H[i] = (float)Hd[i];
  float s[6] = {0,0,0,0,0,0};
  for (int c = 0; c < NC; ++c) {
    float* sp = sig + ((size_t)c * NB + r) * 6;
    #pragma unroll
    for (int i = 0; i < 6; ++i) sp[i] = s[i];
    const float* ep = eout + ((size_t)c * NB + r) * 6;
    float ns[6];
    #pragma unroll
    for (int i = 0; i < 6; ++i) {
      float acc = ep[i];
      #pragma unroll
      for (int k = 0; k < 6; ++k) acc += H[i*6+k] * s[k];
      ns[i] = acc;
    }
    #pragma unroll
    for (int i = 0; i < 6; ++i) s[i] = ns[i];
  }
}

// K4: exact cascade per chunk with true entry state; writes final output.
__global__ __launch_bounds__(64) void eq_k4(
    const float* __restrict__ x, const float* __restrict__ fc,
    const float* __restrict__ sig, float* __restrict__ y)
{
  __shared__ float lds[64 * 128];
  const int l = threadIdx.x;
  const int bid = blockIdx.x;
  const int r = bid / GPB, g = bid % GPB;
  const float b01=fc[0],  b11=fc[1],  b21=fc[2],  a11=fc[3],  a21=fc[4];
  const float b02=fc[8],  b12=fc[9],  b22=fc[10], a12=fc[11], a22=fc[12];
  const float b03=fc[16], b13=fc[17], b23=fc[18], a13=fc[19], a23=fc[20];
  const float* xr = x + (size_t)r * NT;
  const float* xg = xr + g * 64 * CL;
  float* yg = y + (size_t)r * NT + g * 64 * CL;
  const int chunk = g * 64 + l;
  const int t0 = chunk * CL;
  float x1 = 0.f, x2 = 0.f;
  if (t0 > 0) { x1 = xr[t0-1]; x2 = xr[t0-2]; }
  const float* sp = sig + ((size_t)chunk * NB + r) * 6;
  float y1p=sp[0], y1pp=sp[1], y2p=sp[2], y2pp=sp[3], y3p=sp[4], y3pp=sp[5];
  for (int st = 0; st < NSTEP; ++st) {
    const int j0 = st * STEP;
    __syncthreads();                   // protect tile reuse (store below read it)
    #pragma unroll
    for (int i = 0; i < 25; ++i) {
      int f = i * 64 + l;
      int seg = f / 25, off = f % 25;
      float4 v = *(const float4*)(xg + seg*CL + j0 + off*4);
      *(float4*)(&lds[seg*128 + (((off + seg) & 31) << 2)]) = v;
    }
    __syncthreads();
    #pragma unroll
    for (int jq = 0; jq < 25; ++jq) {
      float4 xv = *(const float4*)(&lds[l*128 + (((jq + l) & 31) << 2)]);
      float4 yv;
      #pragma unroll
      for (int q = 0; q < 4; ++q) {
        const float xn = (q==0)?xv.x:(q==1)?xv.y:(q==2)?xv.z:xv.w;
        float y1 = b01*xn + b11*x1  + b21*x2   - a11*y1p - a21*y1pp;
        float y2 = b02*y1 + b12*y1p + b22*y1pp - a12*y2p - a22*y2pp;
        float y3 = b03*y2 + b13*y2p + b23*y2pp - a13*y3p - a23*y3pp;
        x2=x1; x1=xn;
        y1pp=y1p; y1p=y1; y2pp=y2p; y2p=y2; y3pp=y3p; y3p=y3;
        if (q==0) yv.x=y3; else if (q==1) yv.y=y3; else if (q==2) yv.z=y3; else yv.w=y3;
      }
      *(float4*)(&lds[l*128 + (((jq + l) & 31) << 2)]) = yv;
    }
    __syncthreads();
    #pragma unroll
    for (int i = 0; i < 25; ++i) {     // cooperative coalesced store
      int f = i * 64 + l;
      int seg = f / 25, off = f % 25;
      float4 v = *(const float4*)(&lds[seg*128 + (((off + seg) & 31) << 2)]);
      *(float4*)(yg + seg*CL + j0 + off*4) = v;
    }
  }
}

// ---------------------------------------------------------------------------
// Workspace layout (needs ~1.88 MB):
//   [0,    288)  double H[36]
//   [512,  608)  float  fc[24]   (3 filters x {b0,b1,b2,a1,a2}, stride 8)
//   [4096, +983040)  float e[NC][NB][6]     zero-state exit states
//   [.. ,  +983040)  float sigma[NC][NB][6] true entry states
// ---------------------------------------------------------------------------
extern "C" void kernel_launch(void* const* d_in, const int* in_sizes, int n_in,
                              void* d_out, int out_size, void* d_ws, size_t ws_size,
                              hipStream_t stream) {
  const float* clip = (const float*)d_in[0];
  const float* fr   = (const float*)d_in[1];
  const float* gn   = (const float*)d_in[2];
  const float* qs   = (const float*)d_in[3];
  float* out = (float*)d_out;
  char* ws = (char*)d_ws;
  double* Hd = (double*)ws;
  float*  fc = (float*)(ws + 512);
  float*  eo = (float*)(ws + 4096);
  float*  sg = (float*)(ws + 4096 + (size_t)NC * NB * 6 * 4);

  eq_k1<<<1, 64, 0, stream>>>(fr, gn, qs, fc, Hd);
  eq_k2<<<NB * GPB, 64, 0, stream>>>(clip, fc, eo);
  eq_k3<<<4, 32, 0, stream>>>(eo, Hd, sg);
  eq_k4<<<NB * GPB, 64, 0, stream>>>(clip, fc, sg, out);
}

// Round 2
// 88.160 us; speedup vs baseline: 2.1969x; 2.1969x over previous
//
#include <hip/hip_runtime.h>
#include <math.h>

#define SRATE 32000.0
#define NB 128            // batch rows
#define NT 160000         // samples per row
#define CL 100            // chunk length
#define NCROW 1600        // chunks per row (NT/CL)
#define CPB 64            // chunks per block (one lane each)
#define SEG 25            // chunks per lane in K3 scan (NCROW/64)
#define NBLK (NB * NCROW / CPB)   // 3200 blocks for K2/K4

#ifndef M_PI
#define M_PI 3.14159265358979323846
#endif

// ---------------------------------------------------------------------------
// K1: f64 coeffs (reference formula), H = M^CL (6x6 chunk transition),
// G^(2^k) = H^(SEG*2^k) for the K3 Kogge-Stone scan. All f64, cast to f32.
// State: (y1[n-1], y1[n-2], y2[n-1], y2[n-2], y3[n-1], y3[n-2])
// ---------------------------------------------------------------------------
__global__ __launch_bounds__(64) void eq_k1(
    const float* __restrict__ fr, const float* __restrict__ gn,
    const float* __restrict__ qs, float* __restrict__ fc,
    float* __restrict__ Hf, float* __restrict__ Gpf)
{
  __shared__ double dc[24];
  __shared__ double Mb[36], Rb[36], Tb[36];
  const int t = threadIdx.x;
  if (t == 0) {
    for (int f = 0; f < 3; ++f) {
      double w0 = 2.0 * M_PI * (double)fr[f] / SRATE;
      double A  = exp((double)gn[f] / 40.0 * log(10.0));
      double al = sin(w0) / (2.0 * (double)qs[f]);
      double cw = cos(w0);
      double a0 = 1.0 + al / A;
      double b0 = (1.0 + al * A) / a0;
      double b1 = -2.0 * cw / a0;
      double b2 = (1.0 - al * A) / a0;
      double a1 = -2.0 * cw / a0;
      double a2 = (1.0 - al / A) / a0;
      dc[f*8+0]=b0; dc[f*8+1]=b1; dc[f*8+2]=b2; dc[f*8+3]=a1; dc[f*8+4]=a2;
      fc[f*8+0]=(float)b0; fc[f*8+1]=(float)b1; fc[f*8+2]=(float)b2;
      fc[f*8+3]=(float)a1; fc[f*8+4]=(float)a2;
    }
  }
  __syncthreads();
  // one-step matrix M, column t = zero-input step from e_t
  if (t < 6) {
    double s0=0,s1=0,s2=0,s3=0,s4=0,s5=0;
    if (t==0) s0=1; else if (t==1) s1=1; else if (t==2) s2=1;
    else if (t==3) s3=1; else if (t==4) s4=1; else s5=1;
    double y1 = -dc[3]*s0 - dc[4]*s1;
    double y2 = dc[8]*y1 + dc[9]*s0 + dc[10]*s1 - dc[11]*s2 - dc[12]*s3;
    double y3 = dc[16]*y2 + dc[17]*s2 + dc[18]*s3 - dc[19]*s4 - dc[20]*s5;
    Mb[0*6+t] = y1;  Mb[1*6+t] = s0;
    Mb[2*6+t] = y2;  Mb[3*6+t] = s2;
    Mb[4*6+t] = y3;  Mb[5*6+t] = s4;
  }
  if (t < 36) Rb[t] = ((t % 7) == 0) ? 1.0 : 0.0;
  __syncthreads();
  const int i = t / 6, j = t % 6;
  // Rb = Mb^CL  (binary powering; Mb clobbered)
  int e = CL;
  while (e) {
    if (e & 1) {
      double acc = 0.0;
      if (t < 36) { for (int k = 0; k < 6; ++k) acc += Rb[i*6+k]*Mb[k*6+j]; Tb[t]=acc; }
      __syncthreads();
      if (t < 36) Rb[t] = Tb[t];
      __syncthreads();
    }
    e >>= 1;
    if (e) {
      double acc = 0.0;
      if (t < 36) { for (int k = 0; k < 6; ++k) acc += Mb[i*6+k]*Mb[k*6+j]; Tb[t]=acc; }
      __syncthreads();
      if (t < 36) Mb[t] = Tb[t];
      __syncthreads();
    }
  }
  if (t < 36) Hf[t] = (float)Rb[t];   // H = M^CL
  __syncthreads();
  // Mb = H ; Rb = I ; then Rb = H^SEG
  if (t < 36) Mb[t] = Rb[t];
  __syncthreads();
  if (t < 36) Rb[t] = ((t % 7) == 0) ? 1.0 : 0.0;
  __syncthreads();
  e = SEG;
  while (e) {
    if (e & 1) {
      double acc = 0.0;
      if (t < 36) { for (int k = 0; k < 6; ++k) acc += Rb[i*6+k]*Mb[k*6+j]; Tb[t]=acc; }
      __syncthreads();
      if (t < 36) Rb[t] = Tb[t];
      __syncthreads();
    }
    e >>= 1;
    if (e) {
      double acc = 0.0;
      if (t < 36) { for (int k = 0; k < 6; ++k) acc += Mb[i*6+k]*Mb[k*6+j]; Tb[t]=acc; }
      __syncthreads();
      if (t < 36) Mb[t] = Tb[t];
      __syncthreads();
    }
  }
  if (t < 36) Gpf[t] = (float)Rb[t];  // G = H^SEG
  __syncthreads();
  for (int k = 1; k < 6; ++k) {       // Gp[k] = Gp[k-1]^2
    double acc = 0.0;
    if (t < 36) { for (int m = 0; m < 6; ++m) acc += Rb[i*6+m]*Rb[m*6+j]; Tb[t]=acc; }
    __syncthreads();
    if (t < 36) Rb[t] = Tb[t];
    __syncthreads();
    if (t < 36) Gpf[k*36+t] = (float)Rb[t];
    __syncthreads();
  }
}

// ---------------------------------------------------------------------------
// Tile: 64 lanes x 128-float rows (32 KiB). (chunk s, sample j) at
// lds[s*128 + ((j/4 + s)&31)*4 + j%4] — keeps ds_*_b128 at the 8-word/bank
// floor (no excess conflicts). Block covers 64 consecutive GLOBAL chunks
// (6400 floats, contiguous; row boundaries coincide with block boundaries).
// ---------------------------------------------------------------------------

// K2: zero-state cascade per chunk; emit 6-float exit state.
__global__ __launch_bounds__(64) void eq_k2(
    const float* __restrict__ x, const float* __restrict__ fc,
    float* __restrict__ eo)
{
  __shared__ float lds[64 * 128];
  const int l = threadIdx.x;
  const float* xg = x + (size_t)blockIdx.x * (CPB * CL);
  #pragma unroll
  for (int it = 0; it < 25; ++it) {          // coalesced: 1KB contiguous/iter
    int f = it * 64 + l;
    int seg = f / 25, off = f % 25;
    float4 v = *(const float4*)(xg + seg*CL + off*4);
    *(float4*)(&lds[seg*128 + (((off + seg) & 31) << 2)]) = v;
  }
  __syncthreads();
  const int ch = blockIdx.x * CPB + l;
  float x1, x2;
  if (l == 0) {
    if (ch % NCROW == 0) { x1 = 0.f; x2 = 0.f; }
    else { x1 = xg[-1]; x2 = xg[-2]; }
  } else {
    const int ps = l - 1;
    x1 = lds[ps*128 + (((24 + ps) & 31) << 2) + 3];
    x2 = lds[ps*128 + (((24 + ps) & 31) << 2) + 2];
  }
  const float b01=fc[0],  b11=fc[1],  b21=fc[2],  a11=fc[3],  a21=fc[4];
  const float b02=fc[8],  b12=fc[9],  b22=fc[10], a12=fc[11], a22=fc[12];
  const float b03=fc[16], b13=fc[17], b23=fc[18], a13=fc[19], a23=fc[20];
  float y1p=0,y1pp=0,y2p=0,y2pp=0,y3p=0,y3pp=0;
  #pragma unroll
  for (int jq = 0; jq < 25; ++jq) {
    float4 xv = *(const float4*)(&lds[l*128 + (((jq + l) & 31) << 2)]);
    #pragma unroll
    for (int q = 0; q < 4; ++q) {
      const float xn = (q==0)?xv.x:(q==1)?xv.y:(q==2)?xv.z:xv.w;
      float y1 = b01*xn + b11*x1  + b21*x2   - a11*y1p - a21*y1pp;
      float y2 = b02*y1 + b12*y1p + b22*y1pp - a12*y2p - a22*y2pp;
      float y3 = b03*y2 + b13*y2p + b23*y2pp - a13*y3p - a23*y3pp;
      x2=x1; x1=xn;
      y1pp=y1p; y1p=y1; y2pp=y2p; y2p=y2; y3pp=y3p; y3p=y3;
    }
  }
  float* ep = eo + (size_t)ch * 6;
  ep[0]=y1p; ep[1]=y1pp; ep[2]=y2p; ep[3]=y2pp; ep[4]=y3p; ep[5]=y3pp;
}

// ---------------------------------------------------------------------------
// K3: per-row Kogge-Stone scan over 1600 chunks (64 lanes x SEG=25 each).
// sigma' = H*sigma + e. Overwrites e with sigma (entry state) in place.
// ---------------------------------------------------------------------------
__global__ __launch_bounds__(64) void eq_k3(
    float* __restrict__ eo, const float* __restrict__ Hf,
    const float* __restrict__ Gpf)
{
  const int row = blockIdx.x, l = threadIdx.x;
  float H[36];
  #pragma unroll
  for (int i = 0; i < 36; ++i) H[i] = Hf[i];
  float* base = eo + ((size_t)row * NCROW + (size_t)l * SEG) * 6;
  // local zero-entry scan -> E_l
  float u[6] = {0,0,0,0,0,0};
  for (int j = 0; j < SEG; ++j) {
    const float* ep = base + j*6;
    float ev[6]; 
    #pragma unroll
    for (int i = 0; i < 6; ++i) ev[i] = ep[i];
    float nu[6];
    #pragma unroll
    for (int i = 0; i < 6; ++i) {
      float acc = ev[i];
      #pragma unroll
      for (int k = 0; k < 6; ++k) acc += H[i*6+k]*u[k];
      nu[i] = acc;
    }
    #pragma unroll
    for (int i = 0; i < 6; ++i) u[i] = nu[i];
  }
  // Kogge-Stone inclusive scan: t_l += G^(2^k) * t_{l-2^k}
  float t6[6];
  #pragma unroll
  for (int i = 0; i < 6; ++i) t6[i] = u[i];
  #pragma unroll
  for (int k = 0; k < 6; ++k) {
    float G[36];
    #pragma unroll
    for (int i = 0; i < 36; ++i) G[i] = Gpf[k*36+i];
    float o[6];
    #pragma unroll
    for (int i = 0; i < 6; ++i) o[i] = __shfl_up(t6[i], 1u << k, 64);
    if (l >= (1 << k)) {
      float nt[6];
      #pragma unroll
      for (int i = 0; i < 6; ++i) {
        float acc = t6[i];
        #pragma unroll
        for (int m = 0; m < 6; ++m) acc += G[i*6+m]*o[m];
        nt[i] = acc;
      }
      #pragma unroll
      for (int i = 0; i < 6; ++i) t6[i] = nt[i];
    }
  }
  // entry state for this lane's segment = exclusive scan
  float s[6];
  #pragma unroll
  for (int i = 0; i < 6; ++i) s[i] = __shfl_up(t6[i], 1, 64);
  if (l == 0) { 
    #pragma unroll
    for (int i = 0; i < 6; ++i) s[i] = 0.f; 
  }
  // replay: store sigma_c (entry), advance s = e_c + H*s
  for (int j = 0; j < SEG; ++j) {
    float* ep = base + j*6;
    float ev[6];
    #pragma unroll
    for (int i = 0; i < 6; ++i) ev[i] = ep[i];
    #pragma unroll
    for (int i = 0; i < 6; ++i) ep[i] = s[i];
    float ns[6];
    #pragma unroll
    for (int i = 0; i < 6; ++i) {
      float acc = ev[i];
      #pragma unroll
      for (int k = 0; k < 6; ++k) acc += H[i*6+k]*s[k];
      ns[i] = acc;
    }
    #pragma unroll
    for (int i = 0; i < 6; ++i) s[i] = ns[i];
  }
}

// K4: exact cascade per chunk with true entry state; writes final output.
__global__ __launch_bounds__(64) void eq_k4(
    const float* __restrict__ x, const float* __restrict__ fc,
    const float* __restrict__ sg, float* __restrict__ y)
{
  __shared__ float lds[64 * 128];
  const int l = threadIdx.x;
  const float* xg = x + (size_t)blockIdx.x * (CPB * CL);
  float* yg = y + (size_t)blockIdx.x * (CPB * CL);
  #pragma unroll
  for (int it = 0; it < 25; ++it) {
    int f = it * 64 + l;
    int seg = f / 25, off = f % 25;
    float4 v = *(const float4*)(xg + seg*CL + off*4);
    *(float4*)(&lds[seg*128 + (((off + seg) & 31) << 2)]) = v;
  }
  __syncthreads();
  const int ch = blockIdx.x * CPB + l;
  float x1, x2;
  if (l == 0) {
    if (ch % NCROW == 0) { x1 = 0.f; x2 = 0.f; }
    else { x1 = xg[-1]; x2 = xg[-2]; }
  } else {
    const int ps = l - 1;
    x1 = lds[ps*128 + (((24 + ps) & 31) << 2) + 3];
    x2 = lds[ps*128 + (((24 + ps) & 31) << 2) + 2];
  }
  __syncthreads();   // x1/x2 cross-lane reads done before tile is overwritten
  const float b01=fc[0],  b11=fc[1],  b21=fc[2],  a11=fc[3],  a21=fc[4];
  const float b02=fc[8],  b12=fc[9],  b22=fc[10], a12=fc[11], a22=fc[12];
  const float b03=fc[16], b13=fc[17], b23=fc[18], a13=fc[19], a23=fc[20];
  const float* sp = sg + (size_t)ch * 6;
  float y1p=sp[0], y1pp=sp[1], y2p=sp[2], y2pp=sp[3], y3p=sp[4], y3pp=sp[5];
  #pragma unroll
  for (int jq = 0; jq < 25; ++jq) {
    float4 xv = *(const float4*)(&lds[l*128 + (((jq + l) & 31) << 2)]);
    float4 yv;
    #pragma unroll
    for (int q = 0; q < 4; ++q) {
      const float xn = (q==0)?xv.x:(q==1)?xv.y:(q==2)?xv.z:xv.w;
      float y1 = b01*xn + b11*x1  + b21*x2   - a11*y1p - a21*y1pp;
      float y2 = b02*y1 + b12*y1p + b22*y1pp - a12*y2p - a22*y2pp;
      float y3 = b03*y2 + b13*y2p + b23*y2pp - a13*y3p - a23*y3pp;
      x2=x1; x1=xn;
      y1pp=y1p; y1p=y1; y2pp=y2p; y2p=y2; y3pp=y3p; y3p=y3;
      if (q==0) yv.x=y3; else if (q==1) yv.y=y3; else if (q==2) yv.z=y3; else yv.w=y3;
    }
    *(float4*)(&lds[l*128 + (((jq + l) & 31) << 2)]) = yv;
  }
  __syncthreads();
  #pragma unroll
  for (int it = 0; it < 25; ++it) {
    int f = it * 64 + l;
    int seg = f / 25, off = f % 25;
    float4 v = *(const float4*)(&lds[seg*128 + (((off + seg) & 31) << 2)]);
    *(float4*)(yg + seg*CL + off*4) = v;
  }
}

// ---------------------------------------------------------------------------
// Workspace: [0,96) fc | [256,400) Hf | [512,1376) Gpf[6][36] |
//            [4096, +4.92MB) e/sigma (aliased, overwritten in K3)
// ---------------------------------------------------------------------------
extern "C" void kernel_launch(void* const* d_in, const int* in_sizes, int n_in,
                              void* d_out, int out_size, void* d_ws, size_t ws_size,
                              hipStream_t stream) {
  const float* clip = (const float*)d_in[0];
  const float* fr   = (const float*)d_in[1];
  const float* gn   = (const float*)d_in[2];
  const float* qs   = (const float*)d_in[3];
  float* out = (float*)d_out;
  char* ws = (char*)d_ws;
  float* fc  = (float*)ws;
  float* Hf  = (float*)(ws + 256);
  float* Gpf = (float*)(ws + 512);
  float* eo  = (float*)(ws + 4096);

  eq_k1<<<1, 64, 0, stream>>>(fr, gn, qs, fc, Hf, Gpf);
  eq_k2<<<NBLK, 64, 0, stream>>>(clip, fc, eo);
  eq_k3<<<NB, 64, 0, stream>>>(eo, Hf, Gpf);
  eq_k4<<<NBLK, 64, 0, stream>>>(clip, fc, eo, out);
}